// Round 11
// baseline (552.331 us; speedup 1.0000x reference)
//
#include <hip/hip_runtime.h>
#include <math.h>

#define TB 256

constexpr int B_ = 4, S_ = 2048, HID_ = 1024, H_ = 16, KV_ = 4, D_ = 64;

typedef short sh8 __attribute__((ext_vector_type(8)));   // 8 bf16 in 4 VGPRs
typedef float fl4 __attribute__((ext_vector_type(4)));
typedef unsigned short u16;
typedef unsigned int u32;

__device__ __forceinline__ u16 f2bf(float f) {  // RNE float->bf16 bits
  u32 u = __float_as_uint(f);
  u += 0x7fff + ((u >> 16) & 1);
  return (u16)(u >> 16);
}
__device__ __forceinline__ float bf2f(u16 h) { return __uint_as_float(((u32)h) << 16); }

// ---- workspace layout ----
// u16-unit offsets. A-frag (16x16x32): lane=quad*16+col holds A[m=col][k=quad*8+j].
// B-frag: lane holds B[k=quad*8+j][n=col]. 16B/lane.
constexpr size_t XSZ   = (size_t)B_ * S_ * HID_;          // 8,388,608 per plane
constexpr size_t WQH_O = 2 * XSZ;
constexpr size_t WQSZ  = (size_t)2 * HID_ * (H_ * D_);
constexpr size_t WQL_O = WQH_O + WQSZ;
constexpr size_t WKH_O = WQH_O + 2 * WQSZ;
constexpr size_t WKSZ  = (size_t)2 * HID_ * (KV_ * D_);
constexpr size_t WKL_O = WKH_O + WKSZ;
constexpr size_t KH_O  = WKH_O + 2 * WKSZ;
constexpr size_t KSZ   = (size_t)2 * B_ * KV_ * S_ * D_;
constexpr size_t KL_O  = KH_O + KSZ;
constexpr size_t KPLANE = (size_t)S_ * D_;                 // per (a,b,kv)
// float-unit offsets
constexpr size_t FBASE   = (KH_O + 2 * KSZ) / 2;
constexpr size_t U_OFF   = FBASE;                          // U[a][b][h][k]
constexpr size_t U_SZ    = (size_t)2 * B_ * H_ * S_;
constexpr size_t WVO_OFF = U_OFF + U_SZ;                   // wvoT[c][n]
constexpr size_t WVO_SZ  = (size_t)HID_ * 32;
constexpr size_t SH_OFF  = WVO_OFF + WVO_SZ;               // Sh[a*4+b][q][h]
constexpr size_t SH_SZ   = (size_t)2 * B_ * S_ * H_;
constexpr size_t W_OFF   = SH_OFF + SH_SZ;                 // w[b][q]
constexpr size_t W_SZ    = (size_t)B_ * S_;
constexpr size_t SUM_OFF = W_OFF + W_SZ;                   // 4 doubles

// scale folded into Q fragments at frag build: 1/sqrt(64) * log2(e)
#define QSCALE 0.18033688011112044f

// ==== fused prep1: conv_x [0,512) | conv_w Q [512,768) | conv_w K [768,832) | wvo [832,864) ====
__device__ __forceinline__ void conv_w_body(
    const float* __restrict__ W1, const float* __restrict__ W2,
    u16* __restrict__ OH, u16* __restrict__ OL, int ncols,
    int blk, int tid, float wt[32][257]) {
  int ngrp = ncols >> 8;
  int a = blk / (32 * ngrp);
  int rem = blk - a * 32 * ngrp;
  int cs = rem / ngrp, ng = rem - cs * ngrp;
  const float* W = a ? W2 : W1;
#pragma unroll
  for (int i = 0; i < 8; ++i) {
    int e = tid + i * 256;
    int r = e >> 6, c4 = (e & 63) * 4;
    float4 v = *reinterpret_cast<const float4*>(
        W + ((size_t)(cs * 32 + r)) * ncols + ng * 256 + c4);
    wt[r][c4] = v.x; wt[r][c4 + 1] = v.y; wt[r][c4 + 2] = v.z; wt[r][c4 + 3] = v.w;
  }
  __syncthreads();
  int w = tid >> 6, lane = tid & 63, quad = lane >> 4, col = lane & 15;
  int NF = ncols >> 4;
#pragma unroll
  for (int f = 0; f < 4; ++f) {
    int n16 = w * 4 + f;
    sh8 hh, ll;
#pragma unroll
    for (int j = 0; j < 8; ++j) {
      float v = wt[quad * 8 + j][n16 * 16 + col];
      u16 hb = f2bf(v);
      hh[j] = (short)hb;
      ll[j] = (short)f2bf(v - bf2f(hb));
    }
    size_t fb = (((size_t)a * 32 + cs) * NF + ng * 16 + n16) * 512 + (size_t)lane * 8;
    *reinterpret_cast<sh8*>(OH + fb) = hh;
    *reinterpret_cast<sh8*>(OL + fb) = ll;
  }
}

__global__ __launch_bounds__(TB) void prep1_kernel(
    const float* __restrict__ x,
    const float* __restrict__ Wq1, const float* __restrict__ Wq2,
    const float* __restrict__ Wk1, const float* __restrict__ Wk2,
    const float* __restrict__ Wv1, const float* __restrict__ Wo1,
    const float* __restrict__ Wv2, const float* __restrict__ Wo2,
    float* __restrict__ ws) {
  __shared__ float wt[32][257];
  int blk = blockIdx.x, tid = threadIdx.x;
  u16* wsu = (u16*)ws;
  if (blk < 512) {
    // conv_x: x -> hi/lo bf16 A-fragment planes
    u16* XH = wsu;
    u16* XL = XH + XSZ;
    int bt = blk;
    int w = tid >> 6, lane = tid & 63, quad = lane >> 4, col = lane & 15;
    int b = bt >> 7, t16 = bt & 127;
    const float* row = x + ((size_t)b * S_ + t16 * 16 + col) * HID_;
#pragma unroll
    for (int i = 0; i < 8; ++i) {
      int cs = w + i * 4;
      const float* src = row + cs * 32 + quad * 8;
      float4 v0 = *reinterpret_cast<const float4*>(src);
      float4 v1 = *reinterpret_cast<const float4*>(src + 4);
      float vv[8] = {v0.x, v0.y, v0.z, v0.w, v1.x, v1.y, v1.z, v1.w};
      sh8 hh, ll;
#pragma unroll
      for (int j = 0; j < 8; ++j) {
        u16 hb = f2bf(vv[j]);
        hh[j] = (short)hb;
        ll[j] = (short)f2bf(vv[j] - bf2f(hb));
      }
      size_t fb = ((size_t)bt * 32 + cs) * 512 + (size_t)lane * 8;
      *reinterpret_cast<sh8*>(XH + fb) = hh;
      *reinterpret_cast<sh8*>(XL + fb) = ll;
    }
  } else if (blk < 768) {
    conv_w_body(Wq1, Wq2, wsu + WQH_O, wsu + WQL_O, H_ * D_, blk - 512, tid, wt);
  } else if (blk < 832) {
    conv_w_body(Wk1, Wk2, wsu + WKH_O, wsu + WKL_O, KV_ * D_, blk - 768, tid, wt);
  } else {
    // wvo: fold Wv @ Wo per head (+ zero the fp64 sums once)
    int n = blk - 832, a = n >> 4, h = n & 15, kv = h >> 2;
    if (n == 0 && tid < 8) ws[SUM_OFF + tid] = 0.f;
    const float* Wv = a ? Wv2 : Wv1;
    const float* Wo = a ? Wo2 : Wo1;
    for (int c = tid; c < HID_; c += TB) {
      const float* vr = Wv + (size_t)c * (KV_ * D_) + kv * D_;
      const float* wo = Wo + h * D_;
      float acc = 0.f;
#pragma unroll 16
      for (int d = 0; d < D_; ++d) acc += vr[d] * wo[d];
      ws[WVO_OFF + (size_t)c * 32 + n] = acc;
    }
  }
}

// ==== fused prep2: k_gemm [0,1024) | u_gemm [1024,1152) ====
__global__ __launch_bounds__(TB) void prep2_kernel(
    const float* __restrict__ x, float* __restrict__ ws) {
  __shared__ __align__(16) float xs[64][68];
  __shared__ float uw[64][36];
  int blk = blockIdx.x, tid = threadIdx.x;
  if (blk < 1024) {
    // K projection via MFMA (a=0: 3-term, a=1: 1-term) -> B-frag planes
    int k0 = (blk & 31) * 64;
    int kv = (blk >> 5) & 3;
    int ab = blk >> 7, a = ab >> 2, b = ab & 3;
    int w = tid >> 6, lane = tid & 63, quad = lane >> 4, col = lane & 15;
    const u16* XH = (const u16*)ws;
    const u16* XL = XH + XSZ;
    const u16* WKH = XH + WKH_O;
    const u16* WKL = XH + WKL_O;
    int tq = (w & 1) * 2, nq = (w >> 1) * 2;
    fl4 C[2][2] = {};
#pragma unroll 2
    for (int cs = 0; cs < 32; ++cs) {
      sh8 ah[2], al[2], bh[2], bl[2];
#pragma unroll
      for (int ti = 0; ti < 2; ++ti) {
        size_t fb = (((size_t)b * 128 + (k0 >> 4) + tq + ti) * 32 + cs) * 512 + (size_t)lane * 8;
        ah[ti] = *reinterpret_cast<const sh8*>(XH + fb);
        if (a == 0) al[ti] = *reinterpret_cast<const sh8*>(XL + fb);
      }
#pragma unroll
      for (int ni = 0; ni < 2; ++ni) {
        size_t fb = (((size_t)a * 32 + cs) * 16 + kv * 4 + nq + ni) * 512 + (size_t)lane * 8;
        bh[ni] = *reinterpret_cast<const sh8*>(WKH + fb);
        if (a == 0) bl[ni] = *reinterpret_cast<const sh8*>(WKL + fb);
      }
#pragma unroll
      for (int ti = 0; ti < 2; ++ti)
#pragma unroll
        for (int ni = 0; ni < 2; ++ni) {
          C[ti][ni] = __builtin_amdgcn_mfma_f32_16x16x32_bf16(ah[ti], bh[ni], C[ti][ni], 0, 0, 0);
          if (a == 0) {
            C[ti][ni] = __builtin_amdgcn_mfma_f32_16x16x32_bf16(al[ti], bh[ni], C[ti][ni], 0, 0, 0);
            C[ti][ni] = __builtin_amdgcn_mfma_f32_16x16x32_bf16(ah[ti], bl[ni], C[ti][ni], 0, 0, 0);
          }
        }
    }
#pragma unroll
    for (int ti = 0; ti < 2; ++ti)
#pragma unroll
      for (int ni = 0; ni < 2; ++ni)
#pragma unroll
        for (int r = 0; r < 4; ++r)
          xs[(tq + ti) * 16 + quad * 4 + r][(nq + ni) * 16 + col] = C[ti][ni][r];
    __syncthreads();
    u16* KH = (u16*)ws + KH_O;
    u16* KL = (u16*)ws + KL_O;
    size_t plane = (size_t)((a * B_ + b) * KV_ + kv) * KPLANE;
#pragma unroll
    for (int t = 0; t < 2; ++t) {
      int f = w + t * 4;
      int k16 = f & 3, ds = f >> 2;
      const float* row = &xs[k16 * 16 + col][ds * 32 + quad * 8];
      sh8 hh, ll;
#pragma unroll
      for (int j = 0; j < 8; ++j) {
        float v = row[j];
        u16 hb = f2bf(v);
        hh[j] = (short)hb;
        ll[j] = (short)f2bf(v - bf2f(hb));
      }
      size_t fb = plane + ((size_t)(((k0 >> 4) + k16) * 2 + ds)) * 512 + (size_t)lane * 8;
      *reinterpret_cast<sh8*>(KH + fb) = hh;
      if (a == 0) *reinterpret_cast<sh8*>(KL + fb) = ll;
    }
  } else {
    // u_gemm: U = x @ wvoT (fp32 vector; small)
    int i = blk - 1024;
    int k0 = (i & 31) * 64, b = i >> 5;
    int tk = tid >> 2, ng = tid & 3;
    int lr = tid >> 4, lc4 = (tid & 15) * 4;
    float acc[8] = {};
    for (int c0 = 0; c0 < HID_; c0 += 64) {
      __syncthreads();
#pragma unroll
      for (int p = 0; p < 4; ++p) {
        int r = lr + p * 16;
        *reinterpret_cast<float4*>(&xs[r][lc4]) =
            *reinterpret_cast<const float4*>(x + ((size_t)(b * S_ + k0 + r) * HID_ + c0 + lc4));
      }
      {
        int cc = tid >> 3, n4 = (tid & 7) * 4;
        *reinterpret_cast<float4*>(&uw[cc][n4]) =
            *reinterpret_cast<const float4*>(ws + WVO_OFF + (size_t)(c0 + cc) * 32 + n4);
        *reinterpret_cast<float4*>(&uw[cc + 32][n4]) =
            *reinterpret_cast<const float4*>(ws + WVO_OFF + (size_t)(c0 + cc + 32) * 32 + n4);
      }
      __syncthreads();
#pragma unroll 8
      for (int cc = 0; cc < 64; ++cc) {
        float xv = xs[tk][cc];
        float4 a0 = *reinterpret_cast<const float4*>(&uw[cc][ng * 8]);
        float4 a1 = *reinterpret_cast<const float4*>(&uw[cc][ng * 8 + 4]);
        acc[0] += xv * a0.x; acc[1] += xv * a0.y; acc[2] += xv * a0.z; acc[3] += xv * a0.w;
        acc[4] += xv * a1.x; acc[5] += xv * a1.y; acc[6] += xv * a1.z; acc[7] += xv * a1.w;
      }
    }
#pragma unroll
    for (int j = 0; j < 8; ++j) {
      int n = ng * 8 + j, a = n >> 4, h = n & 15;
      ws[U_OFF + ((size_t)(a * B_ + b) * H_ + h) * S_ + k0 + tk] = acc[j];
    }
  }
}

// ---- fused attention: 2 heads per block, double-buffered K stream ----
// grid (32, 16 = a*8+headpair, 4). a=0: 3-term hi/lo; a=1: 1-term bf16.
// One barrier per K tile: prefetch(kt+1)->regs | barrier | compute(kt) | ds_write(kt+1).
__global__ __launch_bounds__(TB, 4) void attn_kernel(float* __restrict__ ws) {
  __shared__ __align__(16) char smem[2 * 8192 * 2];  // 32768 B: Qt overlays buf0
  float (*Qt)[68] = reinterpret_cast<float(*)[68]>(smem);  // 17408 B, phase A only
  u16* kbuf0 = reinterpret_cast<u16*>(smem);
  u16* kbuf1 = kbuf0 + 8192;
  int q0 = blockIdx.x * 64;
  int ah = blockIdx.y, a = ah >> 3, hp = ah & 7;
  int h0 = hp * 2, kv = hp >> 1;
  int b = blockIdx.z;
  int tid = threadIdx.x, w = tid >> 6, lane = tid & 63, quad = lane >> 4, col = lane & 15;
  const u16* XH = (const u16*)ws;
  const u16* XL = XH + XSZ;
  const u16* WQH = XH + WQH_O;
  const u16* WQL = XH + WQL_O;

  // Phase A: per head e in {0,1}: Qt = x_tile @ Wq[:, h*64..h*64+64) -> A-frags
  sh8 qh[2][2], ql[2][2];
#pragma unroll
  for (int e = 0; e < 2; ++e) {
    int h = h0 + e;
    int tq = (w & 1) * 2, nq = (w >> 1) * 2;
    fl4 C[2][2] = {};
#pragma unroll 2
    for (int cs = 0; cs < 32; ++cs) {
      sh8 ah_[2], al_[2], bh_[2], bl_[2];
#pragma unroll
      for (int ti = 0; ti < 2; ++ti) {
        size_t fb = (((size_t)b * 128 + (q0 >> 4) + tq + ti) * 32 + cs) * 512 + (size_t)lane * 8;
        ah_[ti] = *reinterpret_cast<const sh8*>(XH + fb);
        if (a == 0) al_[ti] = *reinterpret_cast<const sh8*>(XL + fb);
      }
#pragma unroll
      for (int ni = 0; ni < 2; ++ni) {
        size_t fb = (((size_t)a * 32 + cs) * 64 + h * 4 + nq + ni) * 512 + (size_t)lane * 8;
        bh_[ni] = *reinterpret_cast<const sh8*>(WQH + fb);
        if (a == 0) bl_[ni] = *reinterpret_cast<const sh8*>(WQL + fb);
      }
#pragma unroll
      for (int ti = 0; ti < 2; ++ti)
#pragma unroll
        for (int ni = 0; ni < 2; ++ni) {
          C[ti][ni] = __builtin_amdgcn_mfma_f32_16x16x32_bf16(ah_[ti], bh_[ni], C[ti][ni], 0, 0, 0);
          if (a == 0) {
            C[ti][ni] = __builtin_amdgcn_mfma_f32_16x16x32_bf16(al_[ti], bh_[ni], C[ti][ni], 0, 0, 0);
            C[ti][ni] = __builtin_amdgcn_mfma_f32_16x16x32_bf16(ah_[ti], bl_[ni], C[ti][ni], 0, 0, 0);
          }
        }
    }
    __syncthreads();  // previous Qt readers (e=1: frag build of e=0) done
#pragma unroll
    for (int ti = 0; ti < 2; ++ti)
#pragma unroll
      for (int ni = 0; ni < 2; ++ni)
#pragma unroll
        for (int r = 0; r < 4; ++r)
          Qt[(nq + ni) * 16 + col][(tq + ti) * 16 + quad * 4 + r] = C[ti][ni][r];
    __syncthreads();
    // Build scaled Q A-fragments (QSCALE folded; phase-B exp becomes raw exp2)
#pragma unroll
    for (int ds = 0; ds < 2; ++ds)
#pragma unroll
      for (int j = 0; j < 8; ++j) {
        float v = Qt[ds * 32 + quad * 8 + j][w * 16 + col] * QSCALE;
        u16 hb = f2bf(v);
        qh[e][ds][j] = (short)hb;
        if (a == 0) ql[e][ds][j] = (short)f2bf(v - bf2f(hb));
      }
  }

  // Phase B: double-buffered K stream, one barrier per tile.
  const u16* KHg = (const u16*)ws + KH_O + (size_t)((a * B_ + b) * KV_ + kv) * KPLANE;
  const u16* KLg = (const u16*)ws + KL_O + (size_t)((a * B_ + b) * KV_ + kv) * KPLANE;
  int nld = (a == 0) ? 4 : 2;
  const u16* srcp[4];
#pragma unroll
  for (int i = 0; i < 4; ++i) {
    if (i < nld) {
      int c = tid + TB * i, f = c >> 6, ln = c & 63;
      if (a == 0) {
        int st = f >> 2, ds = (f >> 1) & 1, p = f & 1;
        srcp[i] = (p ? KLg : KHg) + ((size_t)(st * 2 + ds)) * 512 + (size_t)ln * 8;
      } else {
        int st = f >> 1, ds = f & 1;
        srcp[i] = KHg + ((size_t)(st * 2 + ds)) * 512 + (size_t)ln * 8;
      }
    }
  }
  const float* up0 = ws + U_OFF + ((size_t)(a * B_ + b) * H_ + h0) * S_ + col;
  const float* up1 = up0 + S_;
  // prologue: tile 0 -> regs; after Qt frag reads complete, write into buf0
  uint4 rg[4];
#pragma unroll
  for (int i = 0; i < 4; ++i)
    if (i < nld) {
      rg[i] = *reinterpret_cast<const uint4*>(srcp[i]);
      srcp[i] += 4096;
    }
  __syncthreads();  // all Qt reads done before buf0 (same memory) is overwritten
#pragma unroll
  for (int i = 0; i < 4; ++i)
    if (i < nld)
      *reinterpret_cast<uint4*>(kbuf0 + (size_t)(tid + TB * i) * 8) = rg[i];
  float num[2][4] = {}, den[2][4] = {};
  for (int kt = 0; kt < 32; ++kt) {
    if (kt < 31) {
#pragma unroll
      for (int i = 0; i < 4; ++i)
        if (i < nld) {
          rg[i] = *reinterpret_cast<const uint4*>(srcp[i]);
          srcp[i] += 4096;
        }
    }
    __syncthreads();  // tile kt's ds_writes visible; prior readers of next buf done
    float uv[2][4];
#pragma unroll
    for (int st = 0; st < 4; ++st) { uv[0][st] = up0[st * 16]; uv[1][st] = up1[st * 16]; }
    up0 += 64; up1 += 64;
    const sh8* kb = (const sh8*)((kt & 1) ? kbuf1 : kbuf0);
#pragma unroll
    for (int st = 0; st < 4; ++st) {
      sh8 bh0, bh1, bl0, bl1;
      if (a == 0) {
        bh0 = kb[(st * 4 + 0) * 64 + lane];
        bl0 = kb[(st * 4 + 1) * 64 + lane];
        bh1 = kb[(st * 4 + 2) * 64 + lane];
        bl1 = kb[(st * 4 + 3) * 64 + lane];
      } else {
        bh0 = kb[(st * 2 + 0) * 64 + lane];
        bh1 = kb[(st * 2 + 1) * 64 + lane];
      }
#pragma unroll
      for (int e = 0; e < 2; ++e) {
        fl4 C = {0.f, 0.f, 0.f, 0.f};
        C = __builtin_amdgcn_mfma_f32_16x16x32_bf16(qh[e][0], bh0, C, 0, 0, 0);
        C = __builtin_amdgcn_mfma_f32_16x16x32_bf16(qh[e][1], bh1, C, 0, 0, 0);
        if (a == 0) {
          C = __builtin_amdgcn_mfma_f32_16x16x32_bf16(ql[e][0], bh0, C, 0, 0, 0);
          C = __builtin_amdgcn_mfma_f32_16x16x32_bf16(ql[e][1], bh1, C, 0, 0, 0);
          C = __builtin_amdgcn_mfma_f32_16x16x32_bf16(qh[e][0], bl0, C, 0, 0, 0);
          C = __builtin_amdgcn_mfma_f32_16x16x32_bf16(qh[e][1], bl1, C, 0, 0, 0);
        }
#pragma unroll
        for (int r = 0; r < 4; ++r) {
          float ex = __builtin_amdgcn_exp2f(C[r]);  // scale pre-folded into Q
          den[e][r] += ex;
          num[e][r] += ex * uv[e][st];
        }
      }
    }
    if (kt < 31) {
      u16* kw = (kt & 1) ? kbuf0 : kbuf1;  // write tile kt+1 into the other buffer
#pragma unroll
      for (int i = 0; i < 4; ++i)
        if (i < nld)
          *reinterpret_cast<uint4*>(kw + (size_t)(tid + TB * i) * 8) = rg[i];
    }
  }
#pragma unroll
  for (int off = 1; off < 16; off <<= 1)
#pragma unroll
    for (int e = 0; e < 2; ++e)
#pragma unroll
      for (int r = 0; r < 4; ++r) {
        den[e][r] += __shfl_xor(den[e][r], off);
        num[e][r] += __shfl_xor(num[e][r], off);
      }
  if (col == 0) {
#pragma unroll
    for (int e = 0; e < 2; ++e)
#pragma unroll
      for (int r = 0; r < 4; ++r) {
        int q = q0 + w * 16 + quad * 4 + r;
        ws[SH_OFF + ((size_t)(a * B_ + b) * S_ + q) * H_ + h0 + e] = num[e][r] / den[e][r];
      }
  }
}

// ---- sum heads; w = sigmoid(s2); fp64 reduce sigmoid(s1) per batch ----
__global__ __launch_bounds__(TB) void post_kernel(float* __restrict__ ws) {
  int g = blockIdx.x * TB + threadIdx.x;
  int b = g >> 11, q = g & (S_ - 1);
  const float* sh = ws + SH_OFF;
  float s1 = 0.f, s2 = 0.f;
#pragma unroll
  for (int h = 0; h < H_; ++h) {
    s1 += sh[((size_t)b * S_ + q) * H_ + h];
    s2 += sh[((size_t)(B_ + b) * S_ + q) * H_ + h];
  }
  ws[W_OFF + g] = 1.f / (1.f + expf(-s2));
  double sig = 1.0 / (1.0 + exp(-(double)s1));
#pragma unroll
  for (int off = 1; off < 64; off <<= 1) sig += __shfl_xor(sig, off);
  __shared__ double red[4];
  int tid = threadIdx.x;
  if ((tid & 63) == 0) red[tid >> 6] = sig;
  __syncthreads();
  if (tid == 0)
    atomicAdd(reinterpret_cast<double*>(ws + SUM_OFF) + b,
              red[0] + red[1] + red[2] + red[3]);
}

// ---- weighted segment pooling; per-block size recompute (deterministic fp64) ----
__global__ __launch_bounds__(TB) void pool_kernel(
    const float* __restrict__ x, const float* __restrict__ scale_p,
    const float* __restrict__ ws, float* __restrict__ out, int max_len) {
  int p = blockIdx.x, b = blockIdx.y;
  // identical arithmetic in every block -> identical sz (deterministic fp64)
  double m = reinterpret_cast<const double*>(ws + SUM_OFF)[b] / (double)S_;
  double v = m * (double)(*scale_p) * (double)(8192 - 32) + 32.0;
  int sz = (int)v;  // truncation, matches .astype(int32)
  int s = p - (max_len - sz);
  int tid = threadIdx.x;
  size_t obase = ((size_t)b * max_len + p) * HID_;
  size_t maskbase = (size_t)B_ * max_len * HID_;
  size_t sizebase = maskbase + (size_t)B_ * max_len;
  if (p == 0 && tid == 0) out[sizebase + b] = (float)sz;
  if (s < 0) {
    *reinterpret_cast<float4*>(out + obase + tid * 4) = make_float4(0.f, 0.f, 0.f, 0.f);
    if (tid == 0) out[maskbase + (size_t)b * max_len + p] = 0.f;
    return;
  }
  double step = (double)S_ / (double)sz;  // np.linspace step in fp64
  int t0 = (int)floor((double)s * step);
  int t1 = (s + 1 == sz) ? S_ : (int)floor((double)(s + 1) * step);
  const float* wv = ws + W_OFF + (size_t)b * S_;
  const float* xb = x + (size_t)b * S_ * HID_;
  float den = 0.f, acc0 = 0.f, acc1 = 0.f, acc2 = 0.f, acc3 = 0.f;
  for (int t = t0; t < t1; ++t) {
    float wt = wv[t];
    den += wt;
    float4 xv = *reinterpret_cast<const float4*>(xb + (size_t)t * HID_ + tid * 4);
    acc0 += xv.x * wt; acc1 += xv.y * wt; acc2 += xv.z * wt; acc3 += xv.w * wt;
  }
  float d = den + 1e-8f;
  *reinterpret_cast<float4*>(out + obase + tid * 4) =
      make_float4(acc0 / d, acc1 / d, acc2 / d, acc3 / d);
  if (tid == 0) out[maskbase + (size_t)b * max_len + p] = 1.f;
}

extern "C" void kernel_launch(void* const* d_in, const int* in_sizes, int n_in,
                              void* d_out, int out_size, void* d_ws, size_t ws_size,
                              hipStream_t stream) {
  const float* x    = (const float*)d_in[0];
  const float* Wq1  = (const float*)d_in[1];
  const float* Wk1  = (const float*)d_in[2];
  const float* Wv1  = (const float*)d_in[3];
  const float* Wo1  = (const float*)d_in[4];
  const float* Wq2  = (const float*)d_in[5];
  const float* Wk2  = (const float*)d_in[6];
  const float* Wv2  = (const float*)d_in[7];
  const float* Wo2  = (const float*)d_in[8];
  const float* scale = (const float*)d_in[9];
  float* ws  = (float*)d_ws;
  float* out = (float*)d_out;

  // out layout: pooled[B][max_len][HID], mask[B][max_len], sizes[B]
  int max_len = (out_size - B_) / (B_ * (HID_ + 1));

  prep1_kernel<<<864, TB, 0, stream>>>(x, Wq1, Wq2, Wk1, Wk2, Wv1, Wo1, Wv2, Wo2, ws);
  prep2_kernel<<<1152, TB, 0, stream>>>(x, ws);
  attn_kernel<<<dim3(S_ / 64, 16, B_), TB, 0, stream>>>(ws);
  post_kernel<<<(B_ * S_) / TB, TB, 0, stream>>>(ws);
  pool_kernel<<<dim3(max_len, B_), TB, 0, stream>>>(x, scale, ws, out, max_len);
}

// Round 12
// 422.756 us; speedup vs baseline: 1.3065x; 1.3065x over previous
//
#include <hip/hip_runtime.h>
#include <math.h>

#define TB 256

constexpr int B_ = 4, S_ = 2048, HID_ = 1024, H_ = 16, KV_ = 4, D_ = 64;

typedef short sh8 __attribute__((ext_vector_type(8)));   // 8 bf16 in 4 VGPRs
typedef float fl4 __attribute__((ext_vector_type(4)));
typedef unsigned short u16;
typedef unsigned int u32;

__device__ __forceinline__ u16 f2bf(float f) {  // RNE float->bf16 bits
  u32 u = __float_as_uint(f);
  u += 0x7fff + ((u >> 16) & 1);
  return (u16)(u >> 16);
}
__device__ __forceinline__ float bf2f(u16 h) { return __uint_as_float(((u32)h) << 16); }

// ---- workspace layout ----
// u16-unit offsets. A-frag (16x16x32): lane=quad*16+col holds A[m=col][k=quad*8+j].
// B-frag: lane holds B[k=quad*8+j][n=col]. 16B/lane.
constexpr size_t XSZ   = (size_t)B_ * S_ * HID_;          // 8,388,608 per plane
constexpr size_t WQH_O = 2 * XSZ;
constexpr size_t WQSZ  = (size_t)2 * HID_ * (H_ * D_);
constexpr size_t WQL_O = WQH_O + WQSZ;
constexpr size_t WKH_O = WQH_O + 2 * WQSZ;
constexpr size_t WKSZ  = (size_t)2 * HID_ * (KV_ * D_);
constexpr size_t WKL_O = WKH_O + WKSZ;
constexpr size_t KH_O  = WKH_O + 2 * WKSZ;
constexpr size_t KSZ   = (size_t)2 * B_ * KV_ * S_ * D_;
constexpr size_t KL_O  = KH_O + KSZ;
constexpr size_t KPLANE = (size_t)S_ * D_;                 // per (a,b,kv)
// float-unit offsets
constexpr size_t FBASE   = (KH_O + 2 * KSZ) / 2;
constexpr size_t U_OFF   = FBASE;                          // U[a][b][h][k]
constexpr size_t U_SZ    = (size_t)2 * B_ * H_ * S_;
constexpr size_t WVO_OFF = U_OFF + U_SZ;                   // wvoT[c][n]
constexpr size_t WVO_SZ  = (size_t)HID_ * 32;
constexpr size_t SH_OFF  = WVO_OFF + WVO_SZ;               // Sh[a*4+b][q][h]
constexpr size_t SH_SZ   = (size_t)2 * B_ * S_ * H_;
constexpr size_t W_OFF   = SH_OFF + SH_SZ;                 // w[b][q]
constexpr size_t W_SZ    = (size_t)B_ * S_;
constexpr size_t SUM_OFF = W_OFF + W_SZ;                   // 4 doubles

// scale folded into Q fragments at frag build: 1/sqrt(64) * log2(e)
#define QSCALE 0.18033688011112044f

// ==== fused prep1: conv_x [0,512) | conv_w Q [512,768) | conv_w K [768,832) | wvo [832,864) ====
__device__ __forceinline__ void conv_w_body(
    const float* __restrict__ W1, const float* __restrict__ W2,
    u16* __restrict__ OH, u16* __restrict__ OL, int ncols,
    int blk, int tid, float wt[32][257]) {
  int ngrp = ncols >> 8;
  int a = blk / (32 * ngrp);
  int rem = blk - a * 32 * ngrp;
  int cs = rem / ngrp, ng = rem - cs * ngrp;
  const float* W = a ? W2 : W1;
#pragma unroll
  for (int i = 0; i < 8; ++i) {
    int e = tid + i * 256;
    int r = e >> 6, c4 = (e & 63) * 4;
    float4 v = *reinterpret_cast<const float4*>(
        W + ((size_t)(cs * 32 + r)) * ncols + ng * 256 + c4);
    wt[r][c4] = v.x; wt[r][c4 + 1] = v.y; wt[r][c4 + 2] = v.z; wt[r][c4 + 3] = v.w;
  }
  __syncthreads();
  int w = tid >> 6, lane = tid & 63, quad = lane >> 4, col = lane & 15;
  int NF = ncols >> 4;
#pragma unroll
  for (int f = 0; f < 4; ++f) {
    int n16 = w * 4 + f;
    sh8 hh, ll;
#pragma unroll
    for (int j = 0; j < 8; ++j) {
      float v = wt[quad * 8 + j][n16 * 16 + col];
      u16 hb = f2bf(v);
      hh[j] = (short)hb;
      ll[j] = (short)f2bf(v - bf2f(hb));
    }
    size_t fb = (((size_t)a * 32 + cs) * NF + ng * 16 + n16) * 512 + (size_t)lane * 8;
    *reinterpret_cast<sh8*>(OH + fb) = hh;
    *reinterpret_cast<sh8*>(OL + fb) = ll;
  }
}

__global__ __launch_bounds__(TB) void prep1_kernel(
    const float* __restrict__ x,
    const float* __restrict__ Wq1, const float* __restrict__ Wq2,
    const float* __restrict__ Wk1, const float* __restrict__ Wk2,
    const float* __restrict__ Wv1, const float* __restrict__ Wo1,
    const float* __restrict__ Wv2, const float* __restrict__ Wo2,
    float* __restrict__ ws) {
  __shared__ float wt[32][257];
  int blk = blockIdx.x, tid = threadIdx.x;
  u16* wsu = (u16*)ws;
  if (blk < 512) {
    // conv_x: x -> hi/lo bf16 A-fragment planes
    u16* XH = wsu;
    u16* XL = XH + XSZ;
    int bt = blk;
    int w = tid >> 6, lane = tid & 63, quad = lane >> 4, col = lane & 15;
    int b = bt >> 7, t16 = bt & 127;
    const float* row = x + ((size_t)b * S_ + t16 * 16 + col) * HID_;
#pragma unroll
    for (int i = 0; i < 8; ++i) {
      int cs = w + i * 4;
      const float* src = row + cs * 32 + quad * 8;
      float4 v0 = *reinterpret_cast<const float4*>(src);
      float4 v1 = *reinterpret_cast<const float4*>(src + 4);
      float vv[8] = {v0.x, v0.y, v0.z, v0.w, v1.x, v1.y, v1.z, v1.w};
      sh8 hh, ll;
#pragma unroll
      for (int j = 0; j < 8; ++j) {
        u16 hb = f2bf(vv[j]);
        hh[j] = (short)hb;
        ll[j] = (short)f2bf(vv[j] - bf2f(hb));
      }
      size_t fb = ((size_t)bt * 32 + cs) * 512 + (size_t)lane * 8;
      *reinterpret_cast<sh8*>(XH + fb) = hh;
      *reinterpret_cast<sh8*>(XL + fb) = ll;
    }
  } else if (blk < 768) {
    conv_w_body(Wq1, Wq2, wsu + WQH_O, wsu + WQL_O, H_ * D_, blk - 512, tid, wt);
  } else if (blk < 832) {
    conv_w_body(Wk1, Wk2, wsu + WKH_O, wsu + WKL_O, KV_ * D_, blk - 768, tid, wt);
  } else {
    // wvo: fold Wv @ Wo per head (+ zero the fp64 sums once)
    int n = blk - 832, a = n >> 4, h = n & 15, kv = h >> 2;
    if (n == 0 && tid < 8) ws[SUM_OFF + tid] = 0.f;
    const float* Wv = a ? Wv2 : Wv1;
    const float* Wo = a ? Wo2 : Wo1;
    for (int c = tid; c < HID_; c += TB) {
      const float* vr = Wv + (size_t)c * (KV_ * D_) + kv * D_;
      const float* wo = Wo + h * D_;
      float acc = 0.f;
#pragma unroll 16
      for (int d = 0; d < D_; ++d) acc += vr[d] * wo[d];
      ws[WVO_OFF + (size_t)c * 32 + n] = acc;
    }
  }
}

// ==== fused prep2: k_gemm [0,1024) | u_gemm [1024,1152) ====
__global__ __launch_bounds__(TB) void prep2_kernel(
    const float* __restrict__ x, float* __restrict__ ws) {
  __shared__ __align__(16) float xs[64][68];
  __shared__ float uw[64][36];
  int blk = blockIdx.x, tid = threadIdx.x;
  if (blk < 1024) {
    // K projection via MFMA (a=0: 3-term, a=1: 1-term) -> B-frag planes
    int k0 = (blk & 31) * 64;
    int kv = (blk >> 5) & 3;
    int ab = blk >> 7, a = ab >> 2, b = ab & 3;
    int w = tid >> 6, lane = tid & 63, quad = lane >> 4, col = lane & 15;
    const u16* XH = (const u16*)ws;
    const u16* XL = XH + XSZ;
    const u16* WKH = XH + WKH_O;
    const u16* WKL = XH + WKL_O;
    int tq = (w & 1) * 2, nq = (w >> 1) * 2;
    fl4 C[2][2] = {};
#pragma unroll 2
    for (int cs = 0; cs < 32; ++cs) {
      sh8 ah[2], al[2], bh[2], bl[2];
#pragma unroll
      for (int ti = 0; ti < 2; ++ti) {
        size_t fb = (((size_t)b * 128 + (k0 >> 4) + tq + ti) * 32 + cs) * 512 + (size_t)lane * 8;
        ah[ti] = *reinterpret_cast<const sh8*>(XH + fb);
        if (a == 0) al[ti] = *reinterpret_cast<const sh8*>(XL + fb);
      }
#pragma unroll
      for (int ni = 0; ni < 2; ++ni) {
        size_t fb = (((size_t)a * 32 + cs) * 16 + kv * 4 + nq + ni) * 512 + (size_t)lane * 8;
        bh[ni] = *reinterpret_cast<const sh8*>(WKH + fb);
        if (a == 0) bl[ni] = *reinterpret_cast<const sh8*>(WKL + fb);
      }
#pragma unroll
      for (int ti = 0; ti < 2; ++ti)
#pragma unroll
        for (int ni = 0; ni < 2; ++ni) {
          C[ti][ni] = __builtin_amdgcn_mfma_f32_16x16x32_bf16(ah[ti], bh[ni], C[ti][ni], 0, 0, 0);
          if (a == 0) {
            C[ti][ni] = __builtin_amdgcn_mfma_f32_16x16x32_bf16(al[ti], bh[ni], C[ti][ni], 0, 0, 0);
            C[ti][ni] = __builtin_amdgcn_mfma_f32_16x16x32_bf16(ah[ti], bl[ni], C[ti][ni], 0, 0, 0);
          }
        }
    }
#pragma unroll
    for (int ti = 0; ti < 2; ++ti)
#pragma unroll
      for (int ni = 0; ni < 2; ++ni)
#pragma unroll
        for (int r = 0; r < 4; ++r)
          xs[(tq + ti) * 16 + quad * 4 + r][(nq + ni) * 16 + col] = C[ti][ni][r];
    __syncthreads();
    u16* KH = (u16*)ws + KH_O;
    u16* KL = (u16*)ws + KL_O;
    size_t plane = (size_t)((a * B_ + b) * KV_ + kv) * KPLANE;
#pragma unroll
    for (int t = 0; t < 2; ++t) {
      int f = w + t * 4;
      int k16 = f & 3, ds = f >> 2;
      const float* row = &xs[k16 * 16 + col][ds * 32 + quad * 8];
      sh8 hh, ll;
#pragma unroll
      for (int j = 0; j < 8; ++j) {
        float v = row[j];
        u16 hb = f2bf(v);
        hh[j] = (short)hb;
        ll[j] = (short)f2bf(v - bf2f(hb));
      }
      size_t fb = plane + ((size_t)(((k0 >> 4) + k16) * 2 + ds)) * 512 + (size_t)lane * 8;
      *reinterpret_cast<sh8*>(KH + fb) = hh;
      if (a == 0) *reinterpret_cast<sh8*>(KL + fb) = ll;
    }
  } else {
    // u_gemm: U = x @ wvoT (fp32 vector; small)
    int i = blk - 1024;
    int k0 = (i & 31) * 64, b = i >> 5;
    int tk = tid >> 2, ng = tid & 3;
    int lr = tid >> 4, lc4 = (tid & 15) * 4;
    float acc[8] = {};
    for (int c0 = 0; c0 < HID_; c0 += 64) {
      __syncthreads();
#pragma unroll
      for (int p = 0; p < 4; ++p) {
        int r = lr + p * 16;
        *reinterpret_cast<float4*>(&xs[r][lc4]) =
            *reinterpret_cast<const float4*>(x + ((size_t)(b * S_ + k0 + r) * HID_ + c0 + lc4));
      }
      {
        int cc = tid >> 3, n4 = (tid & 7) * 4;
        *reinterpret_cast<float4*>(&uw[cc][n4]) =
            *reinterpret_cast<const float4*>(ws + WVO_OFF + (size_t)(c0 + cc) * 32 + n4);
        *reinterpret_cast<float4*>(&uw[cc + 32][n4]) =
            *reinterpret_cast<const float4*>(ws + WVO_OFF + (size_t)(c0 + cc + 32) * 32 + n4);
      }
      __syncthreads();
#pragma unroll 8
      for (int cc = 0; cc < 64; ++cc) {
        float xv = xs[tk][cc];
        float4 a0 = *reinterpret_cast<const float4*>(&uw[cc][ng * 8]);
        float4 a1 = *reinterpret_cast<const float4*>(&uw[cc][ng * 8 + 4]);
        acc[0] += xv * a0.x; acc[1] += xv * a0.y; acc[2] += xv * a0.z; acc[3] += xv * a0.w;
        acc[4] += xv * a1.x; acc[5] += xv * a1.y; acc[6] += xv * a1.z; acc[7] += xv * a1.w;
      }
    }
#pragma unroll
    for (int j = 0; j < 8; ++j) {
      int n = ng * 8 + j, a = n >> 4, h = n & 15;
      ws[U_OFF + ((size_t)(a * B_ + b) * H_ + h) * S_ + k0 + tk] = acc[j];
    }
  }
}

// ---- fused attention: 2 heads per block share each staged K tile (R10 shape) ----
// grid (32, 16 = a*8+headpair, 4). a=0: 3-term hi/lo; a=1: 1-term bf16.
// Staging via async global->LDS DMA (__builtin_amdgcn_global_load_lds, 16B/lane):
// no VGPR round-trip, no ds_write VALU — the m97-ladder staging structure.
__global__ __launch_bounds__(TB, 4) void attn_kernel(float* __restrict__ ws) {
  __shared__ __align__(16) char smem[64 * 68 * 4];  // 17408 B: Qt union kbuf
  float (*Qt)[68] = reinterpret_cast<float(*)[68]>(smem);
  u16* kbuf = reinterpret_cast<u16*>(smem);
  int q0 = blockIdx.x * 64;
  int ah = blockIdx.y, a = ah >> 3, hp = ah & 7;
  int h0 = hp * 2, kv = hp >> 1;
  int b = blockIdx.z;
  int tid = threadIdx.x, w = tid >> 6, lane = tid & 63, quad = lane >> 4, col = lane & 15;
  const u16* XH = (const u16*)ws;
  const u16* XL = XH + XSZ;
  const u16* WQH = XH + WQH_O;
  const u16* WQL = XH + WQL_O;

  // Phase A: per head e in {0,1}: Qt = x_tile @ Wq[:, h*64..h*64+64) -> A-frags
  sh8 qh[2][2], ql[2][2];
#pragma unroll
  for (int e = 0; e < 2; ++e) {
    int h = h0 + e;
    int tq = (w & 1) * 2, nq = (w >> 1) * 2;
    fl4 C[2][2] = {};
#pragma unroll 2
    for (int cs = 0; cs < 32; ++cs) {
      sh8 ah_[2], al_[2], bh_[2], bl_[2];
#pragma unroll
      for (int ti = 0; ti < 2; ++ti) {
        size_t fb = (((size_t)b * 128 + (q0 >> 4) + tq + ti) * 32 + cs) * 512 + (size_t)lane * 8;
        ah_[ti] = *reinterpret_cast<const sh8*>(XH + fb);
        if (a == 0) al_[ti] = *reinterpret_cast<const sh8*>(XL + fb);
      }
#pragma unroll
      for (int ni = 0; ni < 2; ++ni) {
        size_t fb = (((size_t)a * 32 + cs) * 64 + h * 4 + nq + ni) * 512 + (size_t)lane * 8;
        bh_[ni] = *reinterpret_cast<const sh8*>(WQH + fb);
        if (a == 0) bl_[ni] = *reinterpret_cast<const sh8*>(WQL + fb);
      }
#pragma unroll
      for (int ti = 0; ti < 2; ++ti)
#pragma unroll
        for (int ni = 0; ni < 2; ++ni) {
          C[ti][ni] = __builtin_amdgcn_mfma_f32_16x16x32_bf16(ah_[ti], bh_[ni], C[ti][ni], 0, 0, 0);
          if (a == 0) {
            C[ti][ni] = __builtin_amdgcn_mfma_f32_16x16x32_bf16(al_[ti], bh_[ni], C[ti][ni], 0, 0, 0);
            C[ti][ni] = __builtin_amdgcn_mfma_f32_16x16x32_bf16(ah_[ti], bl_[ni], C[ti][ni], 0, 0, 0);
          }
        }
    }
    __syncthreads();  // previous Qt readers (e=1: frag build of e=0) done
#pragma unroll
    for (int ti = 0; ti < 2; ++ti)
#pragma unroll
      for (int ni = 0; ni < 2; ++ni)
#pragma unroll
        for (int r = 0; r < 4; ++r)
          Qt[(nq + ni) * 16 + col][(tq + ti) * 16 + quad * 4 + r] = C[ti][ni][r];
    __syncthreads();
    // Build scaled Q A-fragments (QSCALE folded; phase-B exp becomes raw exp2)
#pragma unroll
    for (int ds = 0; ds < 2; ++ds)
#pragma unroll
      for (int j = 0; j < 8; ++j) {
        float v = Qt[ds * 32 + quad * 8 + j][w * 16 + col] * QSCALE;
        u16 hb = f2bf(v);
        qh[e][ds][j] = (short)hb;
        if (a == 0) ql[e][ds][j] = (short)f2bf(v - bf2f(hb));
      }
  }

  // Phase B: stage each K frag tile once via async global->LDS, run both heads.
  const u16* KHg = (const u16*)ws + KH_O + (size_t)((a * B_ + b) * KV_ + kv) * KPLANE;
  const u16* KLg = (const u16*)ws + KL_O + (size_t)((a * B_ + b) * KV_ + kv) * KPLANE;
  int nld = (a == 0) ? 4 : 2;
  const u16* srcp[4];
#pragma unroll
  for (int i = 0; i < 4; ++i) {
    if (i < nld) {
      int c = tid + TB * i, f = c >> 6, ln = c & 63;
      if (a == 0) {
        int st = f >> 2, ds = (f >> 1) & 1, p = f & 1;
        srcp[i] = (p ? KLg : KHg) + ((size_t)(st * 2 + ds)) * 512 + (size_t)ln * 8;
      } else {
        int st = f >> 1, ds = f & 1;
        srcp[i] = KHg + ((size_t)(st * 2 + ds)) * 512 + (size_t)ln * 8;
      }
    }
  }
  const float* up0 = ws + U_OFF + ((size_t)(a * B_ + b) * H_ + h0) * S_ + col;
  const float* up1 = up0 + S_;
  float num[2][4] = {}, den[2][4] = {};
  for (int kt = 0; kt < 32; ++kt) {
    __syncthreads();  // kbuf readers done (prev iter) / Qt frag reads done (kt=0)
#pragma unroll
    for (int i = 0; i < 4; ++i)
      if (i < nld) {
        // dest: wave-uniform base (kbuf + w*1024B + i*4096B); HW adds lane*16B.
        __builtin_amdgcn_global_load_lds(
            (const __attribute__((address_space(1))) unsigned int*)srcp[i],
            (__attribute__((address_space(3))) unsigned int*)(kbuf + (size_t)w * 512 + (size_t)i * 2048),
            16, 0, 0);
        srcp[i] += 4096;
      }
    __syncthreads();  // drains vmcnt -> staged tile visible
    float uv[2][4];
#pragma unroll
    for (int st = 0; st < 4; ++st) { uv[0][st] = up0[st * 16]; uv[1][st] = up1[st * 16]; }
    up0 += 64; up1 += 64;
    const sh8* kb = (const sh8*)kbuf;
#pragma unroll
    for (int st = 0; st < 4; ++st) {
      sh8 bh0, bh1, bl0, bl1;
      if (a == 0) {
        bh0 = kb[(st * 4 + 0) * 64 + lane];
        bl0 = kb[(st * 4 + 1) * 64 + lane];
        bh1 = kb[(st * 4 + 2) * 64 + lane];
        bl1 = kb[(st * 4 + 3) * 64 + lane];
      } else {
        bh0 = kb[(st * 2 + 0) * 64 + lane];
        bh1 = kb[(st * 2 + 1) * 64 + lane];
      }
#pragma unroll
      for (int e = 0; e < 2; ++e) {
        fl4 C = {0.f, 0.f, 0.f, 0.f};
        C = __builtin_amdgcn_mfma_f32_16x16x32_bf16(qh[e][0], bh0, C, 0, 0, 0);
        C = __builtin_amdgcn_mfma_f32_16x16x32_bf16(qh[e][1], bh1, C, 0, 0, 0);
        if (a == 0) {
          C = __builtin_amdgcn_mfma_f32_16x16x32_bf16(ql[e][0], bh0, C, 0, 0, 0);
          C = __builtin_amdgcn_mfma_f32_16x16x32_bf16(ql[e][1], bh1, C, 0, 0, 0);
          C = __builtin_amdgcn_mfma_f32_16x16x32_bf16(qh[e][0], bl0, C, 0, 0, 0);
          C = __builtin_amdgcn_mfma_f32_16x16x32_bf16(qh[e][1], bl1, C, 0, 0, 0);
        }
#pragma unroll
        for (int r = 0; r < 4; ++r) {
          float ex = __builtin_amdgcn_exp2f(C[r]);  // scale pre-folded into Q
          den[e][r] += ex;
          num[e][r] += ex * uv[e][st];
        }
      }
    }
  }
#pragma unroll
  for (int off = 1; off < 16; off <<= 1)
#pragma unroll
    for (int e = 0; e < 2; ++e)
#pragma unroll
      for (int r = 0; r < 4; ++r) {
        den[e][r] += __shfl_xor(den[e][r], off);
        num[e][r] += __shfl_xor(num[e][r], off);
      }
  if (col == 0) {
#pragma unroll
    for (int e = 0; e < 2; ++e)
#pragma unroll
      for (int r = 0; r < 4; ++r) {
        int q = q0 + w * 16 + quad * 4 + r;
        ws[SH_OFF + ((size_t)(a * B_ + b) * S_ + q) * H_ + h0 + e] = num[e][r] / den[e][r];
      }
  }
}

// ---- sum heads; w = sigmoid(s2); fp64 reduce sigmoid(s1) per batch ----
__global__ __launch_bounds__(TB) void post_kernel(float* __restrict__ ws) {
  int g = blockIdx.x * TB + threadIdx.x;
  int b = g >> 11, q = g & (S_ - 1);
  const float* sh = ws + SH_OFF;
  float s1 = 0.f, s2 = 0.f;
#pragma unroll
  for (int h = 0; h < H_; ++h) {
    s1 += sh[((size_t)b * S_ + q) * H_ + h];
    s2 += sh[((size_t)(B_ + b) * S_ + q) * H_ + h];
  }
  ws[W_OFF + g] = 1.f / (1.f + expf(-s2));
  double sig = 1.0 / (1.0 + exp(-(double)s1));
#pragma unroll
  for (int off = 1; off < 64; off <<= 1) sig += __shfl_xor(sig, off);
  __shared__ double red[4];
  int tid = threadIdx.x;
  if ((tid & 63) == 0) red[tid >> 6] = sig;
  __syncthreads();
  if (tid == 0)
    atomicAdd(reinterpret_cast<double*>(ws + SUM_OFF) + b,
              red[0] + red[1] + red[2] + red[3]);
}

// ---- weighted segment pooling; per-block size recompute (deterministic fp64) ----
__global__ __launch_bounds__(TB) void pool_kernel(
    const float* __restrict__ x, const float* __restrict__ scale_p,
    const float* __restrict__ ws, float* __restrict__ out, int max_len) {
  int p = blockIdx.x, b = blockIdx.y;
  // identical arithmetic in every block -> identical sz (deterministic fp64)
  double m = reinterpret_cast<const double*>(ws + SUM_OFF)[b] / (double)S_;
  double v = m * (double)(*scale_p) * (double)(8192 - 32) + 32.0;
  int sz = (int)v;  // truncation, matches .astype(int32)
  int s = p - (max_len - sz);
  int tid = threadIdx.x;
  size_t obase = ((size_t)b * max_len + p) * HID_;
  size_t maskbase = (size_t)B_ * max_len * HID_;
  size_t sizebase = maskbase + (size_t)B_ * max_len;
  if (p == 0 && tid == 0) out[sizebase + b] = (float)sz;
  if (s < 0) {
    *reinterpret_cast<float4*>(out + obase + tid * 4) = make_float4(0.f, 0.f, 0.f, 0.f);
    if (tid == 0) out[maskbase + (size_t)b * max_len + p] = 0.f;
    return;
  }
  double step = (double)S_ / (double)sz;  // np.linspace step in fp64
  int t0 = (int)floor((double)s * step);
  int t1 = (s + 1 == sz) ? S_ : (int)floor((double)(s + 1) * step);
  const float* wv = ws + W_OFF + (size_t)b * S_;
  const float* xb = x + (size_t)b * S_ * HID_;
  float den = 0.f, acc0 = 0.f, acc1 = 0.f, acc2 = 0.f, acc3 = 0.f;
  for (int t = t0; t < t1; ++t) {
    float wt = wv[t];
    den += wt;
    float4 xv = *reinterpret_cast<const float4*>(xb + (size_t)t * HID_ + tid * 4);
    acc0 += xv.x * wt; acc1 += xv.y * wt; acc2 += xv.z * wt; acc3 += xv.w * wt;
  }
  float d = den + 1e-8f;
  *reinterpret_cast<float4*>(out + obase + tid * 4) =
      make_float4(acc0 / d, acc1 / d, acc2 / d, acc3 / d);
  if (tid == 0) out[maskbase + (size_t)b * max_len + p] = 1.f;
}

extern "C" void kernel_launch(void* const* d_in, const int* in_sizes, int n_in,
                              void* d_out, int out_size, void* d_ws, size_t ws_size,
                              hipStream_t stream) {
  const float* x    = (const float*)d_in[0];
  const float* Wq1  = (const float*)d_in[1];
  const float* Wk1  = (const float*)d_in[2];
  const float* Wv1  = (const float*)d_in[3];
  const float* Wo1  = (const float*)d_in[4];
  const float* Wq2  = (const float*)d_in[5];
  const float* Wk2  = (const float*)d_in[6];
  const float* Wv2  = (const float*)d_in[7];
  const float* Wo2  = (const float*)d_in[8];
  const float* scale = (const float*)d_in[9];
  float* ws  = (float*)d_ws;
  float* out = (float*)d_out;

  // out layout: pooled[B][max_len][HID], mask[B][max_len], sizes[B]
  int max_len = (out_size - B_) / (B_ * (HID_ + 1));

  prep1_kernel<<<864, TB, 0, stream>>>(x, Wq1, Wq2, Wk1, Wk2, Wv1, Wo1, Wv2, Wo2, ws);
  prep2_kernel<<<1152, TB, 0, stream>>>(x, ws);
  attn_kernel<<<dim3(S_ / 64, 16, B_), TB, 0, stream>>>(ws);
  post_kernel<<<(B_ * S_) / TB, TB, 0, stream>>>(ws);
  pool_kernel<<<dim3(max_len, B_), TB, 0, stream>>>(x, scale, ws, out, max_len);
}